// Round 10
// baseline (254.338 us; speedup 1.0000x reference)
//
#include <hip/hip_runtime.h>
#include <cstdint>
#include <cfloat>
#include <math.h>

#define VCAB 128000
#define NROWS 256
#define NTH 1024
#define NWAVE 16
#define NBUCK 4096
#define CAPW 256
#define CKN 1024

__device__ __forceinline__ unsigned mono(float f) {
    unsigned u = __float_as_uint(f);
    return (u & 0x80000000u) ? ~u : (u | 0x80000000u);
}
__device__ __forceinline__ float unmono(unsigned k) {
    return __uint_as_float((k & 0x80000000u) ? (k ^ 0x80000000u) : ~k);
}

// Wave 0 only (lanes 0..63). Scan hist downward from startb; return largest
// bucket b such that suffix-count(>= b) >= 64. Assumes total count >= 64.
__device__ __forceinline__ unsigned find_bstar_wave(const unsigned* hist, int startb, int lane) {
    int hb = startb;
    unsigned cum = 0u;
    for (int it = 0; it < 80; ++it) {
        int b = hb - lane;
        unsigned c = (b >= 0 && b < NBUCK) ? hist[b] : 0u;
        unsigned p = c;                         // inclusive prefix over lanes 0..lane
        #pragma unroll
        for (int off = 1; off < 64; off <<= 1) {
            unsigned q = __shfl_up(p, off, 64);
            if (lane >= off) p += q;
        }
        unsigned long long mm = __ballot(cum + p >= 64u);
        if (mm) {
            int l = __builtin_ctzll(mm);        // first crossing lane = highest bucket
            int b2 = hb - l;
            return (unsigned)(b2 > 0 ? b2 : 0);
        }
        cum += __shfl(p, 63, 64);
        hb -= 64;
        if (hb < 0) return 0u;
    }
    return 0u;
}

__global__ __launch_bounds__(NTH) void sampler_kernel(
    const float* __restrict__ logits,
    const float* __restrict__ gumbel,
    const int* __restrict__ topk_p,
    float* __restrict__ out)
{
    const int row = blockIdx.x;
    const int t = threadIdx.x;
    const int lane = t & 63;
    const int wid = t >> 6;
    const size_t base = (size_t)row * VCAB;
    const float4* rowv = reinterpret_cast<const float4*>(logits + base);

    __shared__ unsigned hist[NBUCK];                  // 16 KB
    __shared__ unsigned long long candW[NWAVE * CAPW]; // 32 KB: per-wave segments
    __shared__ unsigned long long ck[CKN];            // 8 KB
    __shared__ unsigned wcnts[NWAVE];
    __shared__ unsigned candCnt2;
    __shared__ unsigned sh_bsamp, sh_bfin;
    __shared__ float red[16], red2[16];
    __shared__ float sh_msamp, sh_m0, sh_S;

    #pragma unroll
    for (int j = 0; j < NBUCK / NTH; ++j) hist[t + j * NTH] = 0u;
    __syncthreads();

    // ---- sample pass: first 8192 elements -> sample histogram + sample max ----
    float smax = -FLT_MAX;
    #pragma unroll
    for (int ii = 0; ii < 2; ++ii) {
        float4 x = rowv[t + ii * NTH];
        float vs[4] = {x.x, x.y, x.z, x.w};
        #pragma unroll
        for (int c = 0; c < 4; ++c) {
            float v = vs[c];
            if (!(fabsf(v) <= FLT_MAX)) v = -FLT_MAX;   // sanitize NaN/±inf
            smax = fmaxf(smax, v);
            atomicAdd(&hist[mono(v) >> 20], 1u);
        }
    }
    for (int off = 32; off > 0; off >>= 1) smax = fmaxf(smax, __shfl_xor(smax, off, 64));
    if (lane == 0) red[wid] = smax;
    __syncthreads();
    if (t < 16) {
        float m = red[t];
        #pragma unroll
        for (int off = 8; off > 0; off >>= 1) m = fmaxf(m, __shfl_xor(m, off, 16));
        if (t == 0) sh_msamp = m;
    }
    __syncthreads();
    const float msamp = sh_msamp;

    if (t < 64) {
        unsigned b = find_bstar_wave(hist, (int)(mono(msamp) >> 20), lane);
        if (t == 0) sh_bsamp = b;
    }
    __syncthreads();
    // thrV = lower edge of bucket sh_bsamp: {v >= thrV} == {bucket(v) >= sh_bsamp}
    const float thrV = unmono(sh_bsamp << 20);
    // re-zero hist (reused later for the candidate-only histogram)
    #pragma unroll
    for (int j = 0; j < NBUCK / NTH; ++j) hist[t + j * NTH] = 0u;
    __syncthreads();

    // ---- single main pass: pure stream; atomic-free ballot-compacted push ----
    float sacc[4] = {0.f, 0.f, 0.f, 0.f};
    float lacc[4] = {-FLT_MAX, -FLT_MAX, -FLT_MAX, -FLT_MAX};
    unsigned wcnt = 0u;                           // wave-uniform by construction

#define PROC(XV, IDX)                                                          \
    {                                                                          \
        float vs[4] = {(XV).x, (XV).y, (XV).z, (XV).w};                        \
        _Pragma("unroll")                                                      \
        for (int c = 0; c < 4; ++c) {                                          \
            float v = vs[c];                                                   \
            if (!(fabsf(v) <= FLT_MAX)) v = -FLT_MAX;                          \
            lacc[c] = fmaxf(lacc[c], v);                                       \
            sacc[c] += __expf(v - msamp);                                      \
            bool p = (v >= thrV);                                              \
            unsigned long long mb = __ballot(p);                               \
            if (mb) {                                                          \
                if (p) {                                                       \
                    unsigned prefix = __builtin_amdgcn_mbcnt_hi(               \
                        (unsigned)(mb >> 32),                                  \
                        __builtin_amdgcn_mbcnt_lo((unsigned)mb, 0u));          \
                    unsigned pos = wcnt + prefix;                              \
                    if (pos < CAPW)                                            \
                        candW[wid * CAPW + pos] =                              \
                            ((unsigned long long)mono(v) << 32) |              \
                            (unsigned long long)(~(unsigned)((IDX) * 4 + c));  \
                }                                                              \
                wcnt += (unsigned)__popcll(mb);                                \
            }                                                                  \
        }                                                                      \
    }

    int i = t;
    for (; i + NTH < VCAB / 4; i += 2 * NTH) {    // 2 loads in flight
        float4 xa = rowv[i];
        float4 xb = rowv[i + NTH];
        PROC(xa, i);
        PROC(xb, i + NTH);
    }
    for (; i < VCAB / 4; i += NTH) {
        float4 xa = rowv[i];
        PROC(xa, i);
    }
#undef PROC

    if (lane == 0) wcnts[wid] = wcnt;
    float s = (sacc[0] + sacc[1]) + (sacc[2] + sacc[3]);
    float lmax = fmaxf(fmaxf(lacc[0], lacc[1]), fmaxf(lacc[2], lacc[3]));
    for (int off = 32; off > 0; off >>= 1) {
        lmax = fmaxf(lmax, __shfl_xor(lmax, off, 64));
        s += __shfl_xor(s, off, 64);
    }
    if (lane == 0) { red[wid] = lmax; red2[wid] = s; }
    __syncthreads();
    if (t < 16) {
        float m = red[t], z = red2[t];
        #pragma unroll
        for (int off = 8; off > 0; off >>= 1) {
            m = fmaxf(m, __shfl_xor(m, off, 16));
            z += __shfl_xor(z, off, 16);
        }
        if (t == 0) { sh_m0 = m; sh_S = z; }
    }
    __syncthreads();
    const float S = sh_S;

    bool ovf = false;
    #pragma unroll
    for (int w = 0; w < NWAVE; ++w) ovf |= (wcnts[w] > (unsigned)CAPW);

    // ---- candidate histogram (rebuilt from segments; rare fallback re-scan) ----
    if (!ovf) {
        for (int w = 0; w < NWAVE; ++w) {
            unsigned n = wcnts[w];
            for (unsigned j = t; j < n; j += NTH)
                atomicAdd(&hist[(unsigned)(candW[w * CAPW + j] >> 52)], 1u);
        }
    } else {
        for (int i2 = t; i2 < VCAB / 4; i2 += NTH) {
            float4 x = rowv[i2];
            float vs[4] = {x.x, x.y, x.z, x.w};
            #pragma unroll
            for (int c = 0; c < 4; ++c) {
                float v = vs[c];
                if (!(fabsf(v) <= FLT_MAX)) v = -FLT_MAX;
                if (v >= thrV) atomicAdd(&hist[mono(v) >> 20], 1u);
            }
        }
    }
    __syncthreads();

    if (t < 64) {
        unsigned b = find_bstar_wave(hist, (int)(mono(sh_m0) >> 20), lane);
        if (t == 0) sh_bfin = b;
    }
    __syncthreads();
    const unsigned bfin = sh_bfin;

    ck[t] = 0ull;                                 // pad: 0 sorts last descending
    if (t == 0) candCnt2 = 0u;
    __syncthreads();

    if (!ovf) {
        for (int w = 0; w < NWAVE; ++w) {
            unsigned n = wcnts[w];
            for (unsigned j = t; j < n; j += NTH) {
                unsigned long long e = candW[w * CAPW + j];
                if ((unsigned)(e >> 52) >= bfin) {
                    unsigned pos = atomicAdd(&candCnt2, 1u);
                    if (pos < CKN) ck[pos] = e;
                }
            }
        }
    } else {
        const float thr2 = unmono(bfin << 20);
        for (int i2 = t; i2 < VCAB / 4; i2 += NTH) {
            float4 x = rowv[i2];
            float vs[4] = {x.x, x.y, x.z, x.w};
            #pragma unroll
            for (int c = 0; c < 4; ++c) {
                float v = vs[c];
                if (!(fabsf(v) <= FLT_MAX)) v = -FLT_MAX;
                if (v >= thr2) {
                    unsigned pos = atomicAdd(&candCnt2, 1u);
                    if (pos < CKN)
                        ck[pos] = ((unsigned long long)mono(v) << 32) |
                                  (unsigned long long)(~(unsigned)(i2 * 4 + c));
                }
            }
        }
    }
    __syncthreads();

    // ---- bitonic sort, descending; 256-entry network when it fits ----
    const unsigned nc2 = candCnt2 < (unsigned)CKN ? candCnt2 : (unsigned)CKN;
    const int nsort = (nc2 <= 256u) ? 256 : CKN;
    for (int k = 2; k <= nsort; k <<= 1) {
        for (int j = k >> 1; j > 0; j >>= 1) {
            __syncthreads();
            if (t < nsort) {
                int l = t ^ j;
                if (l > t) {
                    unsigned long long a = ck[t], b = ck[l];
                    bool up = ((t & k) == 0);
                    if (up ? (a < b) : (a > b)) { ck[t] = b; ck[l] = a; }
                }
            }
        }
    }
    __syncthreads();

    // ---- epilogue: first wave on sorted top-64 ----
    if (t < 64) {
        unsigned long long key = ck[t];
        float v = unmono((unsigned)(key >> 32));
        int idx = (int)(~(unsigned)key);
        int K = *topk_p;
        K = min(max(K, 1), 64);

        // exclusive cumulative softmax prob (full-row S, base msamp — scale cancels)
        float p = expf(v - msamp) / S;
        float pref = p;
        for (int off = 1; off < 64; off <<= 1) {
            float xx = __shfl_up(pref, off, 64);
            if (t >= off) pref += xx;
        }
        float Eex = pref - p;
        int M = (int)__popcll(__ballot(Eex <= 0.9f));   // top-p kept prefix length

        int Mfinal;
        if (M >= K) {
            float kth = __shfl(v, K - 1, 64);
            int J = (int)__popcll(__ballot(v >= kth));  // kth-value tie-inclusive
            Mfinal = min(M, J);
        } else {
            Mfinal = M;
        }

        bool act = (t < Mfinal);
        float g  = act ? gumbel[base + (size_t)idx] : 0.f;
        float tt = act ? (v + g) : -FLT_MAX;
        int   ti = act ? idx : 0x7FFFFFFF;
        float bv = v;
        float bt = tt; int bi = ti;
        for (int off = 32; off > 0; off >>= 1) {
            float ot = __shfl_xor(bt, off, 64);
            int   oi = __shfl_xor(bi, off, 64);
            float ov = __shfl_xor(bv, off, 64);
            if (ot > bt || (ot == bt && oi < bi)) { bt = ot; bi = oi; bv = ov; }
        }
        float e = act ? expf(v - msamp) : 0.f;
        float Z = e;
        for (int off = 32; off > 0; off >>= 1) Z += __shfl_xor(Z, off, 64);

        if (t == 0) {
            float conf = expf(bv - msamp) / Z;  // softmax over filtered set at x0
            out[row] = conf;
            out[NROWS + row] = (float)bi;       // sampled index as float
            out[2 * NROWS + row] = conf;
        }
    }
}

extern "C" void kernel_launch(void* const* d_in, const int* in_sizes, int n_in,
                              void* d_out, int out_size, void* d_ws, size_t ws_size,
                              hipStream_t stream) {
    const float* logits = (const float*)d_in[0];
    const float* gumbel = (const float*)d_in[1];
    const int*   topk   = (const int*)d_in[2];
    float* out = (float*)d_out;
    sampler_kernel<<<NROWS, NTH, 0, stream>>>(logits, gumbel, topk, out);
}